// Round 12
// baseline (267.175 us; speedup 1.0000x reference)
//
#include <hip/hip_runtime.h>
#include <hip/hip_bf16.h>
#include <math.h>

#define LOG2PI_F 1.8378770664093453f
#define BN_EPS 1e-5f
#define BATCH 32768

#define K1_ROWS 32
#define NB1 (BATCH / K1_ROWS)    // 1024 blocks
#define WS1 840                  // padded K stride for bf16 W1 (>= 832, mult of 8)
#define NB3 1024                 // blocks for K3 (32 rows each)
#define RPB3 32

typedef __attribute__((ext_vector_type(8))) short bf16x8;
typedef __attribute__((ext_vector_type(4))) float f32x4;

__device__ __forceinline__ short f2bf_s(float f) {
    union { __hip_bfloat16 b; short s; } u;
    u.b = __float2bfloat16(f);
    return u.s;
}
__device__ __forceinline__ float bfs_to_f(short s) {
    return __uint_as_float(((unsigned)(unsigned short)s) << 16);
}

// ---------------- K0: W1 fp32 -> bf16 hi/lo (padded, zero-filled) ----------------
__global__ __launch_bounds__(256) void k0_cvt(
    const float* __restrict__ W1, __hip_bfloat16* __restrict__ w1h,
    __hip_bfloat16* __restrict__ w1l)
{
    int i = blockIdx.x * 256 + threadIdx.x;      // over 32*840 = 26880
    if (i >= 32 * WS1) return;
    int o = i / WS1, k = i - o * WS1;
    float w = (k < 784) ? W1[o * 784 + k] : 0.f;
    __hip_bfloat16 h = __float2bfloat16(w);
    float hf = __bfloat162float(h);
    __hip_bfloat16 l = __float2bfloat16(w - hf);
    w1h[i] = h;
    w1l[i] = l;
}

// ---------------- K1: x@W1.T + b1, ReLU, SPN layer 1 ----------------
struct Step { float4 a0, a1; bf16x8 wh0, wl0, wh1, wl1; };

__device__ __forceinline__ void load_step(
    Step& S, const float* __restrict__ xrow,
    const __hip_bfloat16* __restrict__ wh, const __hip_bfloat16* __restrict__ wl,
    int s, int kgrp, int o0)
{
    int kb = s * 32 + kgrp * 8;
    int kc = (kb < 784) ? kb : 0;       // clamp addr; W zero-pad kills contribution
    S.a0 = *(const float4*)(xrow + kc);
    S.a1 = *(const float4*)(xrow + kc + 4);
    const __hip_bfloat16* ph = wh + o0 * WS1 + kb;
    const __hip_bfloat16* pl = wl + o0 * WS1 + kb;
    S.wh0 = *(const bf16x8*)(ph);
    S.wh1 = *(const bf16x8*)(ph + 16 * WS1);
    S.wl0 = *(const bf16x8*)(pl);
    S.wl1 = *(const bf16x8*)(pl + 16 * WS1);
}

__device__ __forceinline__ void comp_step(const Step& S, f32x4& acc0, f32x4& acc1)
{
    float av[8] = {S.a0.x, S.a0.y, S.a0.z, S.a0.w, S.a1.x, S.a1.y, S.a1.z, S.a1.w};
    bf16x8 ah, al;
    #pragma unroll
    for (int e = 0; e < 8; ++e) {
        float f = av[e];
        short h = f2bf_s(f);
        ah[e] = h;
        al[e] = f2bf_s(f - bfs_to_f(h));
    }
    acc0 = __builtin_amdgcn_mfma_f32_16x16x32_bf16(ah, S.wh0, acc0, 0, 0, 0);
    acc0 = __builtin_amdgcn_mfma_f32_16x16x32_bf16(al, S.wh0, acc0, 0, 0, 0);
    acc0 = __builtin_amdgcn_mfma_f32_16x16x32_bf16(ah, S.wl0, acc0, 0, 0, 0);
    acc1 = __builtin_amdgcn_mfma_f32_16x16x32_bf16(ah, S.wh1, acc1, 0, 0, 0);
    acc1 = __builtin_amdgcn_mfma_f32_16x16x32_bf16(al, S.wh1, acc1, 0, 0, 0);
    acc1 = __builtin_amdgcn_mfma_f32_16x16x32_bf16(ah, S.wl1, acc1, 0, 0, 0);
}

// block 128 threads = 2 waves x 16 rows; grid 1024; 8 blocks/CU target
__global__ __launch_bounds__(128, 4) void k1_gemm_spn1(
    const float* __restrict__ x,
    const __hip_bfloat16* __restrict__ w1h, const __hip_bfloat16* __restrict__ w1l,
    const float* __restrict__ b1,
    const float* __restrict__ mean1, const float* __restrict__ std1, const float* __restrict__ sw1,
    const int* __restrict__ scopes1,
    float* __restrict__ s1, float* __restrict__ partials1)
{
    __shared__ float h_lds[32][33];
    __shared__ float mu_l[1024], inv_l[1024], c0_l[512];
    __shared__ int   sc_l[512];
    __shared__ float b1_l[32];
    __shared__ float sv_l[16][33];

    const int t = threadIdx.x;

    // ---- SPN1 constant tables ----
    for (int il = t; il < 1024; il += 128) {
        int o = il & 15, rest = il >> 4;
        int f = rest & 1, m = (rest >> 1) & 1, p = rest >> 2;
        int ig = ((o * 16 + p) * 2 + m) * 2 + f;
        mu_l[il]  = mean1[ig];
        inv_l[il] = 1.0f / std1[ig];
    }
    for (int il = t; il < 512; il += 128) {
        int o = il & 15, rest = il >> 4;
        int m = rest & 1, p = rest >> 1;
        int igw = (o * 16 + p) * 2;
        float w0 = sw1[igw], w1v = sw1[igw + 1];
        float mx = fmaxf(w0, w1v);
        float lse = mx + __logf(__expf(w0 - mx) + __expf(w1v - mx));
        float wm = (m == 0) ? w0 : w1v;
        int igs = ((o * 16 + p) * 2 + m) * 2;
        c0_l[il] = (wm - lse) - __logf(std1[igs]) - __logf(std1[igs + 1]) - LOG2PI_F;
    }
    for (int il = t; il < 512; il += 128) sc_l[il] = scopes1[il];
    if (t < 32) b1_l[t] = b1[t];

    const int wid  = t >> 6;          // 0..1
    const int lane = t & 63;
    const int row0 = blockIdx.x * K1_ROWS;
    const int kgrp = (lane >> 4) & 3;
    const int o0   = lane & 15;
    const float* xrow = x + (size_t)(row0 + wid * 16 + (lane & 15)) * 784;

    f32x4 acc0 = {0.f, 0.f, 0.f, 0.f};
    f32x4 acc1 = {0.f, 0.f, 0.f, 0.f};

    // ---- 2-deep ping-pong over 25 k-steps ----
    Step SA, SB;
    load_step(SA, xrow, w1h, w1l, 0, kgrp, o0);
    #pragma unroll 1
    for (int pp = 0; pp < 12; ++pp) {
        load_step(SB, xrow, w1h, w1l, 2 * pp + 1, kgrp, o0);
        comp_step(SA, acc0, acc1);
        load_step(SA, xrow, w1h, w1l, 2 * pp + 2, kgrp, o0);
        comp_step(SB, acc0, acc1);
    }
    comp_step(SA, acc0, acc1);        // step 24 (tail clamped, W pad = 0)

    __syncthreads();   // tables + b1_l visible

    // ---- epilogue: bias + ReLU -> h_lds ----
    {
        int col = lane & 15;
        int rbase = wid * 16 + kgrp * 4;
        #pragma unroll
        for (int r = 0; r < 4; ++r) {
            h_lds[rbase + r][col]      = fmaxf(acc0[r] + b1_l[col], 0.f);
            h_lds[rbase + r][16 + col] = fmaxf(acc1[r] + b1_l[16 + col], 0.f);
        }
    }
    __syncthreads();

    // ---- SPN1: 512 (row, o) tasks over 128 threads ----
    for (int task = t; task < 512; task += 128) {
        int row_l = task >> 4, o = task & 15;
        float outv = 0.f;
        for (int p = 0; p < 16; ++p) {
            int f0 = sc_l[o * 32 + 2 * p], f1 = sc_l[o * 32 + 2 * p + 1];
            float x0 = h_lds[row_l][f0];
            float x1 = h_lds[row_l][f1];
            float vm[2];
            #pragma unroll
            for (int m = 0; m < 2; ++m) {
                int base = ((p * 2 + m) * 2) * 16 + o;
                float d0 = (x0 - mu_l[base])      * inv_l[base];
                float d1 = (x1 - mu_l[base + 16]) * inv_l[base + 16];
                vm[m] = c0_l[(p * 2 + m) * 16 + o] - 0.5f * (d0 * d0 + d1 * d1);
            }
            float a  = fmaxf(vm[0], vm[1]);
            float bm = fminf(vm[0], vm[1]);
            outv += a + __logf(1.f + __expf(bm - a));
        }
        s1[(size_t)(row0 + row_l) * 16 + o] = outv;
        sv_l[o][row_l] = outv;
    }
    __syncthreads();

    // ---- per-block centered stats (sum, M2) per output column ----
    if (t < 16) {
        float s = 0.f;
        for (int rr = 0; rr < K1_ROWS; ++rr) s += sv_l[t][rr];
        float mb = s * (1.f / K1_ROWS);
        float m2 = 0.f;
        for (int rr = 0; rr < K1_ROWS; ++rr) { float d = sv_l[t][rr] - mb; m2 += d * d; }
        partials1[blockIdx.x * 32 + t]      = s;
        partials1[blockIdx.x * 32 + 16 + t] = m2;
    }
}

// ---------------- K3: fused BN1-stats + BN1 + SPN layer 2 ----------------
// block 320 threads = 32 rows x 10 outputs; grid 1024
__global__ __launch_bounds__(320, 4) void k3_spn2(
    const float* __restrict__ s1, const float* __restrict__ partials1,
    const float* __restrict__ bn1_w, const float* __restrict__ bn1_b,
    const float* __restrict__ mean2, const float* __restrict__ std2, const float* __restrict__ sw2,
    const int* __restrict__ scopes2,
    float* __restrict__ s2, float* __restrict__ partials2)
{
    __shared__ float mu_l[320], inv_l[320], c0_l[160];
    __shared__ int   sc_l[160];
    __shared__ float v_lds[32][17];
    __shared__ float sv_l[10][33];
    __shared__ float g_l[16], sh_l[16];
    __shared__ double dsum[256];
    __shared__ double dmean[16];

    const int t = threadIdx.x;
    const int row0 = blockIdx.x * RPB3;

    // ---- SPN2 constant tables ----
    if (t < 320) {
        int o = t % 10, rest = t / 10;
        int f = rest & 1, m = (rest >> 1) & 1, p = rest >> 2;
        int ig = ((o * 8 + p) * 2 + m) * 2 + f;
        mu_l[t]  = mean2[ig];
        inv_l[t] = 1.0f / std2[ig];
    }
    if (t < 160) {
        int o = t % 10, rest = t / 10;
        int m = rest & 1, p = rest >> 1;
        int igw = (o * 8 + p) * 2;
        float w0 = sw2[igw], w1 = sw2[igw + 1];
        float mx = fmaxf(w0, w1);
        float lse = mx + __logf(__expf(w0 - mx) + __expf(w1 - mx));
        float wm = (m == 0) ? w0 : w1;
        int igs = ((o * 8 + p) * 2 + m) * 2;
        c0_l[t] = (wm - lse) - __logf(std2[igs]) - __logf(std2[igs + 1]) - LOG2PI_F;
    }
    if (t < 160) sc_l[t] = scopes2[t];

    // ---- fused BN1 stats from partials1 (same fp64 order as old kreduce) ----
    {
        const int o = t & 15, seg = t >> 4;    // threads 0..255: 16 segs x 16
        const int per = NB1 / 16;              // 64
        if (t < 256) {
            double s = 0.0;
            for (int b = seg * per; b < (seg + 1) * per; ++b)
                s += (double)partials1[b * 32 + o];
            dsum[t] = s;
        }
        __syncthreads();
        if (t < 16) {
            double S = 0.0;
            for (int g = 0; g < 16; ++g) S += dsum[g * 16 + t];
            dmean[t] = S / (double)BATCH;
        }
        __syncthreads();
        if (t < 256) {
            double mean = dmean[o];
            double m2 = 0.0;
            for (int b = seg * per; b < (seg + 1) * per; ++b) {
                double bm = (double)partials1[b * 32 + o] / (double)K1_ROWS;
                double d  = bm - mean;
                m2 += (double)partials1[b * 32 + 16 + o] + (double)K1_ROWS * d * d;
            }
            __syncthreads();
            dsum[t] = m2;
        } else {
            __syncthreads();
        }
        __syncthreads();
        if (t < 16) {
            double M2 = 0.0;
            for (int g = 0; g < 16; ++g) M2 += dsum[g * 16 + t];
            double var = M2 / (double)BATCH;
            double gsc = (double)bn1_w[t] / sqrt(var + (double)BN_EPS);
            g_l[t]  = (float)gsc;
            sh_l[t] = (float)((double)bn1_b[t] - dmean[t] * gsc);
        }
    }
    __syncthreads();

    // ---- stage BN'd rows ----
    for (int i = t; i < 512; i += 320) {
        int rl = i >> 4, f = i & 15;
        v_lds[rl][f] = fmaf(s1[(size_t)(row0 + rl) * 16 + f], g_l[f], sh_l[f]);
    }
    __syncthreads();

    const int row_l = t / 10, o = t % 10;
    float outv = 0.f;
    for (int p = 0; p < 8; ++p) {
        int f0 = sc_l[o * 16 + 2 * p], f1 = sc_l[o * 16 + 2 * p + 1];
        float x0 = v_lds[row_l][f0], x1 = v_lds[row_l][f1];
        float vm[2];
        #pragma unroll
        for (int m = 0; m < 2; ++m) {
            int base = ((p * 2 + m) * 2) * 10 + o;
            float d0 = (x0 - mu_l[base])      * inv_l[base];
            float d1 = (x1 - mu_l[base + 10]) * inv_l[base + 10];
            vm[m] = c0_l[(p * 2 + m) * 10 + o] - 0.5f * (d0 * d0 + d1 * d1);
        }
        float a  = fmaxf(vm[0], vm[1]);
        float bm = fminf(vm[0], vm[1]);
        outv += a + __logf(1.f + __expf(bm - a));
    }
    s2[(size_t)(row0 + row_l) * 10 + o] = outv;
    sv_l[o][row_l] = outv;
    __syncthreads();

    if (t < 10) {
        float s = 0.f;
        for (int rr = 0; rr < RPB3; ++rr) s += sv_l[t][rr];
        float mb = s * (1.f / RPB3);
        float m2 = 0.f;
        for (int rr = 0; rr < RPB3; ++rr) { float d = sv_l[t][rr] - mb; m2 += d * d; }
        partials2[blockIdx.x * 20 + t]      = s;
        partials2[blockIdx.x * 20 + 10 + t] = m2;
    }
}

// ---------------- K5: fused BN2-stats + BN2 + final linear + log_softmax ----------
// 256 threads x 128 blocks
__global__ __launch_bounds__(256) void k5_head(
    const float* __restrict__ s2, const float* __restrict__ partials2,
    const float* __restrict__ bn2_w, const float* __restrict__ bn2_b,
    const float* __restrict__ W2, const float* __restrict__ b2,
    float* __restrict__ out)
{
    __shared__ float w2_l[100], b2_l[10], st_l[20];
    __shared__ double dsum[256];
    __shared__ double dmean[16];
    const int t = threadIdx.x;
    if (t < 100) w2_l[t] = W2[t];
    if (t >= 128 && t < 138) b2_l[t - 128] = b2[t - 128];

    // ---- fused BN2 stats from partials2 (same fp64 order as old kreduce) ----
    {
        const int o = t & 15, seg = t >> 4;    // 16 segs x 16
        const int per = NB3 / 16;              // 64
        double s = 0.0;
        if (o < 10)
            for (int b = seg * per; b < (seg + 1) * per; ++b)
                s += (double)partials2[b * 20 + o];
        dsum[t] = s;
        __syncthreads();
        if (t < 16) {
            double S = 0.0;
            for (int g = 0; g < 16; ++g) S += dsum[g * 16 + t];
            dmean[t] = S / (double)BATCH;
        }
        __syncthreads();
        double mean = dmean[o];
        double m2 = 0.0;
        if (o < 10) {
            for (int b = seg * per; b < (seg + 1) * per; ++b) {
                double bm = (double)partials2[b * 20 + o] / (double)RPB3;
                double d  = bm - mean;
                m2 += (double)partials2[b * 20 + 10 + o] + (double)RPB3 * d * d;
            }
        }
        __syncthreads();
        dsum[t] = m2;
        __syncthreads();
        if (t < 10) {
            double M2 = 0.0;
            for (int g = 0; g < 16; ++g) M2 += dsum[g * 16 + t];
            double var = M2 / (double)BATCH;
            double gsc = (double)bn2_w[t] / sqrt(var + (double)BN_EPS);
            st_l[t]      = (float)gsc;
            st_l[10 + t] = (float)((double)bn2_b[t] - dmean[t] * gsc);
        }
    }
    __syncthreads();

    const int row = blockIdx.x * 256 + t;
    const float* sr = s2 + (size_t)row * 10;
    float v[10], l[10];
    #pragma unroll
    for (int i = 0; i < 5; ++i) {
        float2 p = *(const float2*)(sr + 2 * i);
        v[2*i]   = fmaf(p.x, st_l[2*i],   st_l[10 + 2*i]);
        v[2*i+1] = fmaf(p.y, st_l[2*i+1], st_l[10 + 2*i+1]);
    }
    float mx = -1e30f;
    #pragma unroll
    for (int c = 0; c < 10; ++c) {
        float a = b2_l[c];
        #pragma unroll
        for (int o = 0; o < 10; ++o) a = fmaf(w2_l[c * 10 + o], v[o], a);
        l[c] = a;
        mx = fmaxf(mx, a);
    }
    float sum = 0.f;
    #pragma unroll
    for (int c = 0; c < 10; ++c) sum += __expf(l[c] - mx);
    float ls = mx + __logf(sum);
    float* orow = out + (size_t)row * 10;
    #pragma unroll
    for (int c = 0; c < 10; ++c) orow[c] = l[c] - ls;
}

extern "C" void kernel_launch(void* const* d_in, const int* in_sizes, int n_in,
                              void* d_out, int out_size, void* d_ws, size_t ws_size,
                              hipStream_t stream) {
    const float* x      = (const float*)d_in[0];
    const float* W1     = (const float*)d_in[1];
    const float* b1     = (const float*)d_in[2];
    const float* mean1  = (const float*)d_in[3];
    const float* std1   = (const float*)d_in[4];
    const float* sw1    = (const float*)d_in[5];
    const float* bn1_w  = (const float*)d_in[6];
    const float* bn1_b  = (const float*)d_in[7];
    const float* mean2  = (const float*)d_in[8];
    const float* std2   = (const float*)d_in[9];
    const float* sw2    = (const float*)d_in[10];
    const float* bn2_w  = (const float*)d_in[11];
    const float* bn2_b  = (const float*)d_in[12];
    const float* W2     = (const float*)d_in[13];
    const float* b2     = (const float*)d_in[14];
    const int*   sc1    = (const int*)d_in[15];
    const int*   sc2    = (const int*)d_in[16];
    float* out = (float*)d_out;

    // workspace layout
    __hip_bfloat16* w1h = (__hip_bfloat16*)d_ws;           // 32*840
    __hip_bfloat16* w1l = w1h + 32 * WS1;                  // 32*840
    float* fbase = (float*)(w1l + 32 * WS1);               // 16B-aligned
    float* s1  = fbase;                    // 32768*16
    float* s2  = s1 + 32768 * 16;          // 32768*10
    float* p1  = s2 + 32768 * 10;          // 1024*32
    float* p2  = p1 + NB1 * 32;            // 1024*20

    hipLaunchKernelGGL(k0_cvt, dim3((32 * WS1 + 255) / 256), dim3(256), 0, stream,
                       W1, w1h, w1l);
    hipLaunchKernelGGL(k1_gemm_spn1, dim3(NB1), dim3(128), 0, stream,
                       x, w1h, w1l, b1, mean1, std1, sw1, sc1, s1, p1);
    hipLaunchKernelGGL(k3_spn2, dim3(NB3), dim3(320), 0, stream,
                       s1, p1, bn1_w, bn1_b, mean2, std2, sw2, sc2, s2, p2);
    hipLaunchKernelGGL(k5_head, dim3(BATCH / 256), dim3(256), 0, stream,
                       s2, p2, bn2_w, bn2_b, W2, b2, out);
}